// Round 2
// baseline (1225.546 us; speedup 1.0000x reference)
//
#include <hip/hip_runtime.h>

// Problem constants
#define BB 64
#define UU 1024
#define HH 16
#define MM 512
#define DD 4
#define NR 8208   // H*(M+1)
#define NW 8192   // H*M
#define NK 1024   // U

__device__ inline float wave_max(float v) {
    #pragma unroll
    for (int off = 32; off > 0; off >>= 1) v = fmaxf(v, __shfl_xor(v, off));
    return v;
}
__device__ inline float wave_sum(float v) {
    #pragma unroll
    for (int off = 32; off > 0; off >>= 1) v += __shfl_xor(v, off);
    return v;
}

// msump[mc][b][u] = sum_{m in chunk} mem[b,m,u]   grid (B,16), block 256 (4 u/thread)
__global__ __launch_bounds__(256) void k_memsum(const float* __restrict__ mem,
                                                float* __restrict__ msump) {
    const int b = blockIdx.x, mc = blockIdx.y, t = threadIdx.x;
    const float4* src = (const float4*)(mem + (size_t)b * MM * UU);
    float4 s = make_float4(0.f, 0.f, 0.f, 0.f);
    const int m0 = mc * 32;
    #pragma unroll 8
    for (int m = m0; m < m0 + 32; ++m) {
        float4 v = src[(size_t)m * 256 + t];
        s.x += v.x; s.y += v.y; s.z += v.z; s.w += v.w;
    }
    *(float4*)(msump + (size_t)(mc * BB + b) * UU + t * 4) = s;
}

// memstate = (sum_mc msump + out)/513    grid 256, block 256
__global__ void k_prep_r(const float* __restrict__ msump, const float* __restrict__ out,
                         float* __restrict__ memstate) {
    int i = blockIdx.x * 256 + threadIdx.x;
    float s = out[i];
    #pragma unroll
    for (int mc = 0; mc < 16; ++mc) s += msump[i + mc * (BB * UU)];
    memstate[i] = s * (1.0f / 513.0f);
}

// ---------------------------------------------------------------------------
// Skinny GEMM: C[64,N] partial = A[64, kbase:+kchunk] @ W[kbase:.., N]
// block 256 (4 waves); tile 64 rows x 128 cols; wave: 16 rows, lane: 2 cols.
// K-split over blockIdx.y -> pbuf[ks][64][N]. Dynamic LDS = kchunk*64*4 B.
// ---------------------------------------------------------------------------
__global__ __launch_bounds__(256, 2) void k_gemm(const float* __restrict__ A,
                                                 const float* __restrict__ W,
                                                 float* __restrict__ pbuf,
                                                 int N, int kchunk, int kcl2) {
    extern __shared__ float At[];   // [kchunk][64] transposed
    const int t = threadIdx.x;
    const int cb = blockIdx.x * 128;
    const int ks = blockIdx.y;
    const int kbase = ks * kchunk;

    const int n4 = kchunk >> 4;
    const int kq_mask = (kchunk >> 2) - 1;
    for (int i = 0; i < n4; ++i) {
        int idx4 = t + (i << 8);
        int r = idx4 >> kcl2;
        int kq = idx4 & kq_mask;
        float4 v = *(const float4*)(A + r * UU + kbase + (kq << 2));
        int kk = kq << 2;
        At[(kk + 0) * 64 + r] = v.x;
        At[(kk + 1) * 64 + r] = v.y;
        At[(kk + 2) * 64 + r] = v.z;
        At[(kk + 3) * 64 + r] = v.w;
    }
    __syncthreads();

    const int wave = t >> 6;
    const int lane = t & 63;
    const int row0 = wave << 4;
    const int col = cb + (lane << 1);
    const bool wvalid = (col + 2 <= N);
    const float* Wp = W + (size_t)kbase * N + col;

    float acc[16][2];
    #pragma unroll
    for (int r = 0; r < 16; ++r) { acc[r][0] = 0.f; acc[r][1] = 0.f; }

    float2 wb0[8], wb1[8];
    if (wvalid) {
        #pragma unroll
        for (int i = 0; i < 8; ++i) wb0[i] = *(const float2*)(Wp + (size_t)i * N);
    }
    for (int kb = 0; kb < kchunk; kb += 8) {
        if (wvalid && (kb + 8 < kchunk)) {
            #pragma unroll
            for (int i = 0; i < 8; ++i)
                wb1[i] = *(const float2*)(Wp + (size_t)(kb + 8 + i) * N);
        }
        #pragma unroll
        for (int i = 0; i < 8; ++i) {
            const float* ap = &At[(kb + i) * 64 + row0];
            float a[16];
            *(float4*)&a[0]  = *(const float4*)(ap + 0);
            *(float4*)&a[4]  = *(const float4*)(ap + 4);
            *(float4*)&a[8]  = *(const float4*)(ap + 8);
            *(float4*)&a[12] = *(const float4*)(ap + 12);
            float2 wv = wb0[i];
            #pragma unroll
            for (int r = 0; r < 16; ++r) {
                acc[r][0] = fmaf(a[r], wv.x, acc[r][0]);
                acc[r][1] = fmaf(a[r], wv.y, acc[r][1]);
            }
        }
        #pragma unroll
        for (int i = 0; i < 8; ++i) wb0[i] = wb1[i];
    }

    if (wvalid) {
        float* dst = pbuf + (size_t)ks * 64 * N + col;
        #pragma unroll
        for (int r = 0; r < 16; ++r) {
            float2 o; o.x = acc[r][0]; o.y = acc[r][1];
            *(float2*)(dst + (size_t)(row0 + r) * N) = o;
        }
    }
}

// K-split reduce + bias + transpose: outT[b][h][slot] = bias[j] + sum_ks pbuf[ks][b][j],
// j = slot*16+h. grid (B, ceil(N/4096)), block 256. Coalesced both sides via LDS.
__global__ __launch_bounds__(256) void k_redT(const float* __restrict__ pbuf,
                                              const float* __restrict__ bias,
                                              float* __restrict__ outT,
                                              int N, int S, int ksplit) {
    __shared__ float sm[256 * 17];
    const int b = blockIdx.x;
    const int j0 = blockIdx.y * 4096;
    const int nj = min(4096, N - j0);
    const int t = threadIdx.x;

    for (int o = t; o < nj; o += 256) {
        int j = j0 + o;
        float val = bias[j];
        for (int ks = 0; ks < ksplit; ++ks)
            val += pbuf[(size_t)(ks * BB + b) * N + j];
        sm[(o >> 4) * 17 + (o & 15)] = val;
    }
    __syncthreads();

    const int slot0 = j0 >> 4;
    const int ns = nj >> 4;
    if (ns == 256) {
        #pragma unroll
        for (int h = 0; h < 16; ++h)
            outT[(size_t)(b * HH + h) * S + slot0 + t] = sm[t * 17 + h];
    } else {
        for (int idx = t; idx < nj; idx += 256) {
            int h = idx / ns, s = idx - h * ns;
            outT[(size_t)(b * HH + h) * S + slot0 + s] = sm[s * 17 + h];
        }
    }
}

// In-place softmax over each length-S row of T. grid 256 blocks, wave per row.
__global__ __launch_bounds__(256) void k_softmax2(float* __restrict__ T, int S) {
    const int row = blockIdx.x * 4 + (threadIdx.x >> 6);
    const int lane = threadIdx.x & 63;
    float* p = T + (size_t)row * S;
    const int n = (S + 63) >> 6;
    float v[9];
    float mx = -1e30f;
    for (int i = 0; i < n; ++i) {
        int s = lane + (i << 6);
        float val = (s < S) ? p[s] : -1e30f;
        v[i] = val;
        mx = fmaxf(mx, val);
    }
    mx = wave_max(mx);
    float sum = 0.f;
    for (int i = 0; i < n; ++i) {
        int s = lane + (i << 6);
        if (s < S) { v[i] = __expf(v[i] - mx); sum += v[i]; }
    }
    sum = wave_sum(sum);
    const float inv = 1.0f / sum;
    for (int i = 0; i < n; ++i) {
        int s = lane + (i << 6);
        if (s < S) p[s] = v[i] * inv;
    }
}

// ppar[mc][b][u] = sum_{m in chunk} rw[b,h(u),m]*mem[b,m,u]   grid (B,16)
__global__ __launch_bounds__(256) void k_passA(const float* __restrict__ mem,
                                               const float* __restrict__ rwT,
                                               float* __restrict__ ppar) {
    const int b = blockIdx.x, mc = blockIdx.y, t = threadIdx.x;
    const int h = t >> 4;
    const float4* src = (const float4*)(mem + (size_t)b * MM * UU);
    const float* rw = rwT + (size_t)(b * HH + h) * (MM + 1);
    float4 s = make_float4(0.f, 0.f, 0.f, 0.f);
    const int m0 = mc * 32;
    #pragma unroll 8
    for (int m = m0; m < m0 + 32; ++m) {
        float wgt = rw[m];
        float4 v = src[(size_t)m * 256 + t];
        s.x = fmaf(wgt, v.x, s.x); s.y = fmaf(wgt, v.y, s.y);
        s.z = fmaf(wgt, v.z, s.z); s.w = fmaf(wgt, v.w, s.w);
    }
    *(float4*)(ppar + (size_t)(mc * BB + b) * UU + t * 4) = s;
}

// kin = sum_mc ppar + out * rw[b,h,M]    grid 256, block 256
__global__ void k_prep_k(const float* __restrict__ ppar, const float* __restrict__ out,
                         const float* __restrict__ rwT, float* __restrict__ kin) {
    int i = blockIdx.x * 256 + threadIdx.x;
    int b = i >> 10, u = i & 1023;
    int h = u >> 6;
    float s = 0.f;
    #pragma unroll
    for (int mc = 0; mc < 16; ++mc) s += ppar[i + mc * (BB * UU)];
    float r = rwT[(size_t)(b * HH + h) * (MM + 1) + MM];
    kin[i] = fmaf(out[i], r, s);
}

// newval = relu(sum_ks kpartials + bk); on last layer also write out.
__global__ void k_relu(const float* __restrict__ pbuf, const float* __restrict__ bk,
                       float* __restrict__ newval, float* __restrict__ outdst) {
    int i = blockIdx.x * 256 + threadIdx.x;
    int u = i & 1023;
    float v = bk[u];
    #pragma unroll
    for (int ks = 0; ks < 32; ++ks) v += pbuf[i + ks * (BB * UU)];
    v = fmaxf(v, 0.f);
    newval[i] = v;
    if (outdst) outdst[i] = v;
}

// mem' = mem + ww*(nv - mem); partial sums to msump (no atomics). grid (B,16)
__global__ __launch_bounds__(256) void k_update(const float* __restrict__ src,
                                                float* __restrict__ dst,
                                                const float* __restrict__ wwT,
                                                const float* __restrict__ newval,
                                                float* __restrict__ msump, int do_sum) {
    const int b = blockIdx.x, mc = blockIdx.y, t = threadIdx.x;
    const int h = t >> 4;
    const float4* s4 = (const float4*)(src + (size_t)b * MM * UU);
    float4* d4 = (float4*)(dst + (size_t)b * MM * UU);
    const float* ww = wwT + (size_t)(b * HH + h) * MM;
    float4 nv = *(const float4*)(newval + b * UU + t * 4);
    float4 acc = make_float4(0.f, 0.f, 0.f, 0.f);
    const int m0 = mc * 32;
    #pragma unroll 8
    for (int m = m0; m < m0 + 32; ++m) {
        float wgt = ww[m];
        float4 v = s4[(size_t)m * 256 + t];
        v.x = fmaf(wgt, nv.x - v.x, v.x);
        v.y = fmaf(wgt, nv.y - v.y, v.y);
        v.z = fmaf(wgt, nv.z - v.z, v.z);
        v.w = fmaf(wgt, nv.w - v.w, v.w);
        d4[(size_t)m * 256 + t] = v;
        acc.x += v.x; acc.y += v.y; acc.z += v.z; acc.w += v.w;
    }
    if (do_sum)
        *(float4*)(msump + (size_t)(mc * BB + b) * UU + t * 4) = acc;
}

// ---------------------------------------------------------------------------
extern "C" void kernel_launch(void* const* d_in, const int* in_sizes, int n_in,
                              void* d_out, int out_size, void* d_ws, size_t ws_size,
                              hipStream_t stream) {
    const float* x    = (const float*)d_in[0];
    const float* memI = (const float*)d_in[1];
    const float* Wr   = (const float*)d_in[2];
    const float* br   = (const float*)d_in[3];
    const float* Ww   = (const float*)d_in[4];
    const float* bw   = (const float*)d_in[5];
    const float* Wk   = (const float*)d_in[6];
    const float* bk   = (const float*)d_in[7];

    float* outp   = (float*)d_out;        // [B,U]
    float* memOut = outp + BB * UU;       // [B,M,U] working memory

    // workspace layout (~30.5 MB)
    char* w = (char*)d_ws;
    float* pbuf     = (float*)(w + 0);           // 16,809,984 B (8x64x8208 f32)
    float* ppar     = (float*)(w + 16809984);    // 4 MB [16][B][U]
    float* msump    = (float*)(w + 21004288);    // 4 MB [16][B][U]
    float* rwT      = (float*)(w + 25198592);    // [B][H][513]
    float* wwT      = (float*)(w + 27299840);    // [B][H][512]
    float* memstate = (float*)(w + 29396992);    // [B,U]
    float* kin      = (float*)(w + 29659136);    // [B,U]
    float* nv0      = (float*)(w + 29921280);    // [B,U]
    float* nv1      = (float*)(w + 30183424);    // [B,U]

    k_memsum<<<dim3(BB, 16), 256, 0, stream>>>(memI, msump);

    const float* curOut = x;
    const float* curMem = memI;
    for (int l = 0; l < DD; ++l) {
        float* nv = (l & 1) ? nv1 : nv0;
        k_prep_r<<<BB * UU / 256, 256, 0, stream>>>(msump, curOut, memstate);
        // rlog = memstate @ Wr[l]  (N=8208, ksplit=8, kchunk=128)
        k_gemm<<<dim3(65, 8), 256, 128 * 64 * 4, stream>>>(
            memstate, Wr + (size_t)l * UU * NR, pbuf, NR, 128, 5);
        k_redT<<<dim3(BB, 3), 256, 0, stream>>>(pbuf, br + (size_t)l * NR, rwT, NR, MM + 1, 8);
        k_softmax2<<<256, 256, 0, stream>>>(rwT, MM + 1);
        k_passA<<<dim3(BB, 16), 256, 0, stream>>>(curMem, rwT, ppar);
        k_prep_k<<<BB * UU / 256, 256, 0, stream>>>(ppar, curOut, rwT, kin);
        // klog = kin @ Wk[l]  (N=1024, ksplit=32, kchunk=32)
        k_gemm<<<dim3(8, 32), 256, 32 * 64 * 4, stream>>>(
            kin, Wk + (size_t)l * UU * NK, pbuf, NK, 32, 3);
        k_relu<<<BB * UU / 256, 256, 0, stream>>>(pbuf, bk + (size_t)l * NK, nv,
                                                  (l == DD - 1) ? outp : (float*)nullptr);
        // wlog = newval @ Ww[l]  (N=8192, ksplit=8, kchunk=128)
        k_gemm<<<dim3(64, 8), 256, 128 * 64 * 4, stream>>>(
            nv, Ww + (size_t)l * UU * NW, pbuf, NW, 128, 5);
        k_redT<<<dim3(BB, 2), 256, 0, stream>>>(pbuf, bw + (size_t)l * NW, wwT, NW, MM, 8);
        k_softmax2<<<256, 256, 0, stream>>>(wwT, MM);
        k_update<<<dim3(BB, 16), 256, 0, stream>>>(curMem, memOut, wwT, nv, msump,
                                                   (l < DD - 1) ? 1 : 0);
        curMem = memOut;
        curOut = nv;
    }
}